// Round 9
// baseline (312.785 us; speedup 1.0000x reference)
//
#include <hip/hip_runtime.h>

#define NN 50000
#define NE 800000
#define D 128

#define CH 64              // edge chunks
#define EPC (NE / CH)      // 12500 edges per chunk
#define RG 8               // node ranges
#define NPR (NN / RG)      // 6250 nodes per range

typedef short bf16x8 __attribute__((ext_vector_type(8)));
typedef float f32x4 __attribute__((ext_vector_type(4)));

// ---------------- bf16 helpers ----------------

__device__ __forceinline__ unsigned bf16rne(float f) {
  unsigned u = __float_as_uint(f);
  return (u + 0x7fffu + ((u >> 16) & 1u)) >> 16;
}
__device__ __forceinline__ unsigned packbf(float lo, float hi) {
  return bf16rne(lo) | (bf16rne(hi) << 16);
}

// ---------------- CSR build + input conversion, no global atomics -----------
// grid 512 = (chunk c = blockIdx>>3) x (range r = blockIdx&7), 1024 threads.
// Prologue (grid-stride, before barrier): x->bf16 table, W^T bf16 x3,
// zero row NN of both gather tables. Then LDS dual histogram of dst/src.
__global__ __launch_bounds__(1024) void hist_kernel(
    const int* __restrict__ src, const int* __restrict__ dst,
    const float* __restrict__ x, const float* __restrict__ W1,
    const float* __restrict__ W2, const float* __restrict__ W3,
    unsigned short* __restrict__ hbf, unsigned short* __restrict__ tbl2,
    unsigned short* __restrict__ T1, unsigned short* __restrict__ T2,
    unsigned short* __restrict__ T3, int* __restrict__ partial_dst,
    int* __restrict__ partial_src) {
  __shared__ int hd[NPR];
  __shared__ int hs[NPR];
  int tid = threadIdx.x;
  int gid = blockIdx.x * 1024 + tid;  // 0..524287

  // ---- conversion prologue (independent of LDS) ----
  for (int i = gid; i < NN * D / 4; i += 512 * 1024) {  // 1.6M uint2 elems
    float4 v = ((const float4*)x)[i];
    uint2 p;
    p.x = packbf(v.x, v.y);
    p.y = packbf(v.z, v.w);
    ((uint2*)hbf)[i] = p;
  }
  if (gid < 3 * 16384) {  // W^T bf16
    int w = gid >> 14;
    int idx = gid & 16383;
    const float* W = (w == 0) ? W1 : (w == 1) ? W2 : W3;
    unsigned short* T = (w == 0) ? T1 : (w == 1) ? T2 : T3;
    int n = idx >> 7, k = idx & 127;
    T[n * 128 + k] = (unsigned short)bf16rne(W[k * 128 + n]);
  } else if (gid < 3 * 16384 + 32) {  // zero row NN of both tables
    int z = gid - 3 * 16384;
    if (z < 16)
      ((uint4*)(hbf + (size_t)NN * D))[z] = make_uint4(0, 0, 0, 0);
    else
      ((uint4*)(tbl2 + (size_t)NN * D))[z - 16] = make_uint4(0, 0, 0, 0);
  }

  // ---- dual LDS histogram ----
  int c = blockIdx.x >> 3;
  int r = blockIdx.x & 7;
  int base = r * NPR;
  for (int i = tid; i < NPR; i += 1024) { hd[i] = 0; hs[i] = 0; }
  __syncthreads();
  int e0 = c * EPC;
  for (int i = tid; i < EPC; i += 1024) {
    int d = dst[e0 + i];
    int s = src[e0 + i];
    unsigned dr = (unsigned)(d - base);
    unsigned sr = (unsigned)(s - base);
    if (dr < NPR) atomicAdd(&hd[dr], 1);
    if (sr < NPR) atomicAdd(&hs[sr], 1);
  }
  __syncthreads();
  for (int i = tid; i < NPR; i += 1024) {
    partial_dst[c * NN + base + i] = hd[i];
    partial_src[c * NN + base + i] = hs[i];
  }
}

__device__ __forceinline__ int block_excl_scan(int v, int* wsum) {
  int lane = threadIdx.x & 63;
  int w = threadIdx.x >> 6;
  int incl = v;
#pragma unroll
  for (int off = 1; off < 64; off <<= 1) {
    int t = __shfl_up(incl, off);
    if (lane >= off) incl += t;
  }
  if (lane == 63) wsum[w] = incl;
  __syncthreads();
  int wo = 0;
#pragma unroll
  for (int j = 0; j < 4; ++j)
    if (j < w) wo += wsum[j];
  return wo + incl - v;
}

// fused reduce + scan phase 1 (padded degree, ceil16)
__global__ __launch_bounds__(256) void degscan_kernel(int* __restrict__ partial_dst,
                                                      const int* __restrict__ partial_src,
                                                      int* __restrict__ degtmp,
                                                      int* __restrict__ deg_out,
                                                      int* __restrict__ row_ptr,
                                                      int* __restrict__ partials, int N) {
  __shared__ int wsum[4];
  int d = blockIdx.x * 256 + threadIdx.x;
  int run = 0;
  if (d < N) {
#pragma unroll
    for (int c = 0; c < CH; ++c) {
      int v = partial_dst[c * NN + d];
      partial_dst[c * NN + d] = run;
      run += v;
    }
    degtmp[d] = run;
    int ro = 0;
#pragma unroll
    for (int c = 0; c < CH; ++c) ro += partial_src[c * NN + d];
    deg_out[d] = ro;
  }
  int pad = (run + 15) & ~15;
  int excl = block_excl_scan(pad, wsum);
  if (d < N) row_ptr[d] = excl;
  if (threadIdx.x == 255) partials[blockIdx.x] = excl + pad;
}

__global__ __launch_bounds__(256) void scan2(int* __restrict__ partials,
                                             int* __restrict__ row_ptr, int nb, int N) {
  __shared__ int wsum[4];
  int v = (threadIdx.x < nb) ? partials[threadIdx.x] : 0;
  int excl = block_excl_scan(v, wsum);
  if (threadIdx.x < nb) partials[threadIdx.x] = excl;
  if (threadIdx.x == nb - 1) row_ptr[N] = excl + v;
}

__global__ __launch_bounds__(256) void scan3(int* __restrict__ row_ptr,
                                             const int* __restrict__ partials, int N) {
  int i = blockIdx.x * 256 + threadIdx.x;
  if (i < N) row_ptr[i] += partials[blockIdx.x];
}

// fill + pad: LDS cursor scatter; chunk-0 blocks also write dummy-index tails.
__global__ __launch_bounds__(1024) void fill_kernel(const int* __restrict__ src,
                                                    const int* __restrict__ dst,
                                                    const int* __restrict__ row_ptr,
                                                    const int* __restrict__ partial_dst,
                                                    const int* __restrict__ degtmp,
                                                    int* __restrict__ csr_src) {
  __shared__ int cur[NPR];
  int tid = threadIdx.x;
  int c = blockIdx.x >> 3;
  int r = blockIdx.x & 7;
  int base = r * NPR;
  for (int i = tid; i < NPR; i += 1024)
    cur[i] = row_ptr[base + i] + partial_dst[c * NN + base + i];
  if (c == 0) {  // pad tails for this node range (disjoint from scatter targets)
    for (int i = tid; i < NPR; i += 1024) {
      int node = base + i;
      int s = row_ptr[node] + degtmp[node];
      int e = row_ptr[node + 1];
      for (int j = s; j < e; ++j) csr_src[j] = NN;
    }
  }
  __syncthreads();
  int e0 = c * EPC;
  for (int i = tid; i < EPC; i += 1024) {
    int d = dst[e0 + i];
    unsigned dr = (unsigned)(d - base);
    if (dr < NPR) {
      int pos = atomicAdd(&cur[dr], 1);
      csr_src[pos] = src[e0 + i];
    }
  }
}

// ---------------- fused agg + MFMA GEMM (1 node per wave) ----------------
// Block 1024 = 16 waves = 16 nodes (one MFMA row-tile). Phase 1: wave wv
// aggregates node base+wv (quarter-wave per edge, 16 loads in flight -> full
// R6-agg TLP: 3125 blocks x 16 waves = 50000 waves). One __syncthreads.
// Phase 2: waves 0..7 each compute one 16x16 n-tile (4 MFMAs), B-fragments
// from L2-hot WT; waves 8..15 exit. Patch stride 136 -> ln/ln+8 alias =
// 2-way LDS conflict = free.
// AMODE 0: sage (self+avg, /(deg+1)); AMODE 1: gcn (*rsqrt(max(deg,1))).
// GMODE 1: row scale rsqrt(max(deg_out,1)). OUT_BF: bf16 table else f32.
__device__ __forceinline__ void bacc(float* a, uint4 u) {
  a[0] += __uint_as_float(u.x << 16);
  a[1] += __uint_as_float(u.x & 0xffff0000u);
  a[2] += __uint_as_float(u.y << 16);
  a[3] += __uint_as_float(u.y & 0xffff0000u);
  a[4] += __uint_as_float(u.z << 16);
  a[5] += __uint_as_float(u.z & 0xffff0000u);
  a[6] += __uint_as_float(u.w << 16);
  a[7] += __uint_as_float(u.w & 0xffff0000u);
}

template <int AMODE, int GMODE, int OUT_BF>
__global__ __launch_bounds__(1024) void fused_kernel(
    const unsigned short* __restrict__ hb, const int* __restrict__ row_ptr,
    const int* __restrict__ csr_src, const int* __restrict__ degtmp,
    const int* __restrict__ deg_out, const unsigned short* __restrict__ WT,
    const float* __restrict__ bias, float* __restrict__ outf,
    unsigned short* __restrict__ outb, int N) {
  __shared__ unsigned short sA[16 * 136];  // 16-node patch, stride-136 pad
  int tid = threadIdx.x;
  int wv = tid >> 6;
  int lane = tid & 63;
  int q = lane >> 4;    // quarter
  int col = lane & 15;  // 16B granule within row
  int base = blockIdx.x * 16;  // N % 16 == 0: no tail

  // ---- phase 1: this wave aggregates node base+wv ----
  {
    int node = base + wv;
    int start = row_ptr[node];
    int iters = (row_ptr[node + 1] - start) >> 4;
    float a0[8] = {0, 0, 0, 0, 0, 0, 0, 0};
    float a1[8] = {0, 0, 0, 0, 0, 0, 0, 0};
    float a2[8] = {0, 0, 0, 0, 0, 0, 0, 0};
    float a3[8] = {0, 0, 0, 0, 0, 0, 0, 0};
    const int* ce = csr_src + start + q;
    for (int it = 0; it < iters; ++it, ce += 16) {
      int i0 = ce[0];
      int i1 = ce[4];
      int i2 = ce[8];
      int i3 = ce[12];
      uint4 u0 = ((const uint4*)(hb + (size_t)i0 * D))[col];
      uint4 u1 = ((const uint4*)(hb + (size_t)i1 * D))[col];
      uint4 u2 = ((const uint4*)(hb + (size_t)i2 * D))[col];
      uint4 u3 = ((const uint4*)(hb + (size_t)i3 * D))[col];
      bacc(a0, u0);
      bacc(a1, u1);
      bacc(a2, u2);
      bacc(a3, u3);
    }
#pragma unroll
    for (int t = 0; t < 8; ++t) a0[t] = (a0[t] + a1[t]) + (a2[t] + a3[t]);
#pragma unroll
    for (int t = 0; t < 8; ++t) {
      a0[t] += __shfl_xor(a0[t], 16);
      a0[t] += __shfl_xor(a0[t], 32);
    }
    int indeg = degtmp[node];
    if (AMODE == 0) {
      uint4 s = ((const uint4*)(hb + (size_t)node * D))[col];
      float sf[8] = {0, 0, 0, 0, 0, 0, 0, 0};
      bacc(sf, s);
      float inv = 1.0f / (float)(indeg + 1);
#pragma unroll
      for (int t = 0; t < 8; ++t) a0[t] = (a0[t] + sf[t]) * inv;
    } else {
      float sc = rsqrtf(fmaxf((float)indeg, 1.0f));
#pragma unroll
      for (int t = 0; t < 8; ++t) a0[t] *= sc;
    }
    if (q == 0) {
      uint4 p;
      p.x = packbf(a0[0], a0[1]);
      p.y = packbf(a0[2], a0[3]);
      p.z = packbf(a0[4], a0[5]);
      p.w = packbf(a0[6], a0[7]);
      *(uint4*)&sA[wv * 136 + col * 8] = p;
    }
  }
  __syncthreads();

  // ---- phase 2: waves 0..7 each compute one 16x16 n-tile ----
  if (wv >= 8) return;
  int nt = wv;
  int ln = col;  // A row / B col-within-tile
  bf16x8 af[4];
#pragma unroll
  for (int c = 0; c < 4; ++c)
    af[c] = *(const bf16x8*)&sA[ln * 136 + c * 32 + q * 8];
  f32x4 acc = (f32x4){0.f, 0.f, 0.f, 0.f};
  {
    const unsigned short* Wr = WT + (size_t)(nt * 16 + ln) * 128 + q * 8;
    bf16x8 b0 = *(const bf16x8*)(Wr + 0);
    bf16x8 b1 = *(const bf16x8*)(Wr + 32);
    bf16x8 b2 = *(const bf16x8*)(Wr + 64);
    bf16x8 b3 = *(const bf16x8*)(Wr + 96);
    acc = __builtin_amdgcn_mfma_f32_16x16x32_bf16(af[0], b0, acc, 0, 0, 0);
    acc = __builtin_amdgcn_mfma_f32_16x16x32_bf16(af[1], b1, acc, 0, 0, 0);
    acc = __builtin_amdgcn_mfma_f32_16x16x32_bf16(af[2], b2, acc, 0, 0, 0);
    acc = __builtin_amdgcn_mfma_f32_16x16x32_bf16(af[3], b3, acc, 0, 0, 0);
  }
  float b = bias[nt * 16 + ln];
#pragma unroll
  for (int r = 0; r < 4; ++r) {
    int row = base + q * 4 + r;  // always < N (N % 16 == 0)
    float scl = 1.0f;
    if (GMODE == 1) scl = rsqrtf(fmaxf((float)deg_out[row], 1.0f));
    float v = (acc[r] + b) * scl;
    if (OUT_BF)
      outb[(size_t)row * 128 + nt * 16 + ln] = (unsigned short)bf16rne(v);
    else
      outf[(size_t)row * 128 + nt * 16 + ln] = v;
  }
}

// ---------------- launcher ----------------

extern "C" void kernel_launch(void* const* d_in, const int* in_sizes, int n_in,
                              void* d_out, int out_size, void* d_ws, size_t ws_size,
                              hipStream_t stream) {
  const float* x = (const float*)d_in[0];
  const float* W1 = (const float*)d_in[1];
  const float* b1 = (const float*)d_in[2];
  const float* W2 = (const float*)d_in[3];
  const float* b2 = (const float*)d_in[4];
  const float* W3 = (const float*)d_in[5];
  const float* b3 = (const float*)d_in[6];
  const int* src = (const int*)d_in[7];
  const int* dst = (const int*)d_in[8];
  float* out = (float*)d_out;

  const int N = NN;

  // workspace layout (~58 MB)
  unsigned short* hbf = (unsigned short*)d_ws;             // (NN+1)*D bf16
  unsigned short* tbl2 = hbf + (size_t)(NN + 1) * D;       // (NN+1)*D bf16
  unsigned short* WT1 = tbl2 + (size_t)(NN + 1) * D;       // 128*128 bf16
  unsigned short* WT2 = WT1 + D * D;
  unsigned short* WT3 = WT2 + D * D;
  int* partial_dst = (int*)(WT3 + D * D);                  // CH*NN
  int* partial_src = partial_dst + (size_t)CH * NN;        // CH*NN
  int* degtmp = partial_src + (size_t)CH * NN;             // NN
  int* deg_out = degtmp + NN;                              // NN
  int* row_ptr = deg_out + NN;                             // NN+1
  int* partials = row_ptr + NN + 1;                        // 256
  int* csr_src = partials + 256;                           // NE + 16*NN

  const int scanBlocks = (N + 255) / 256;  // 196

  hist_kernel<<<CH * RG, 1024, 0, stream>>>(src, dst, x, W1, W2, W3, hbf, tbl2,
                                            WT1, WT2, WT3, partial_dst, partial_src);
  degscan_kernel<<<scanBlocks, 256, 0, stream>>>(partial_dst, partial_src, degtmp,
                                                 deg_out, row_ptr, partials, N);
  scan2<<<1, 256, 0, stream>>>(partials, row_ptr, scanBlocks, N);
  scan3<<<scanBlocks, 256, 0, stream>>>(row_ptr, partials, N);
  fill_kernel<<<CH * RG, 1024, 0, stream>>>(src, dst, row_ptr, partial_dst, degtmp, csr_src);

  int fusedBlocks = N / 16;  // 3125 (N % 16 == 0)

  // layer 1: sage(x)@W1+b1 -> tbl2
  fused_kernel<0, 0, 1><<<fusedBlocks, 1024, 0, stream>>>(
      hbf, row_ptr, csr_src, degtmp, deg_out, WT1, b1, nullptr, tbl2, N);
  // layer 2: sage(h1)@W2+b2, fold norm_out -> hbf
  fused_kernel<0, 1, 1><<<fusedBlocks, 1024, 0, stream>>>(
      tbl2, row_ptr, csr_src, degtmp, deg_out, WT2, b2, nullptr, hbf, N);
  // layer 3: gcn agg(h2)*norm_in @ W3 + b3 -> out (f32)
  fused_kernel<1, 0, 0><<<fusedBlocks, 1024, 0, stream>>>(
      hbf, row_ptr, csr_src, degtmp, deg_out, WT3, b3, out, nullptr, N);
}

// Round 10
// 286.636 us; speedup vs baseline: 1.0912x; 1.0912x over previous
//
#include <hip/hip_runtime.h>

#define NN 50000
#define NE 800000
#define D 128

#define CH 64              // edge chunks
#define EPC (NE / CH)      // 12500 edges per chunk
#define RG 8               // node ranges
#define NPR (NN / RG)      // 6250 nodes per range

typedef short bf16x8 __attribute__((ext_vector_type(8)));
typedef float f32x4 __attribute__((ext_vector_type(4)));

// ---------------- bf16 helpers ----------------

__device__ __forceinline__ unsigned bf16rne(float f) {
  unsigned u = __float_as_uint(f);
  return (u + 0x7fffu + ((u >> 16) & 1u)) >> 16;
}
__device__ __forceinline__ unsigned packbf(float lo, float hi) {
  return bf16rne(lo) | (bf16rne(hi) << 16);
}

// ---------------- CSR build + input conversion, no global atomics -----------
// grid 512 = (chunk c = blockIdx>>3) x (range r = blockIdx&7), 1024 threads.
// Prologue (grid-stride): x->bf16 table, W^T bf16 x3, zero row NN of hbf.
// Then dual LDS histogram of dst/src.
__global__ __launch_bounds__(1024) void hist_kernel(
    const int* __restrict__ src, const int* __restrict__ dst,
    const float* __restrict__ x, const float* __restrict__ W1,
    const float* __restrict__ W2, const float* __restrict__ W3,
    unsigned short* __restrict__ hbf, unsigned short* __restrict__ T1,
    unsigned short* __restrict__ T2, unsigned short* __restrict__ T3,
    int* __restrict__ partial_dst, int* __restrict__ partial_src) {
  __shared__ int hd[NPR];
  __shared__ int hs[NPR];
  int tid = threadIdx.x;
  int gid = blockIdx.x * 1024 + tid;  // 0..524287

  // ---- conversion prologue ----
  for (int i = gid; i < NN * D / 4; i += 512 * 1024) {  // 1.6M uint2 elems
    float4 v = ((const float4*)x)[i];
    uint2 p;
    p.x = packbf(v.x, v.y);
    p.y = packbf(v.z, v.w);
    ((uint2*)hbf)[i] = p;
  }
  if (gid < 3 * 16384) {  // W^T bf16
    int w = gid >> 14;
    int idx = gid & 16383;
    const float* W = (w == 0) ? W1 : (w == 1) ? W2 : W3;
    unsigned short* T = (w == 0) ? T1 : (w == 1) ? T2 : T3;
    int n = idx >> 7, k = idx & 127;
    T[n * 128 + k] = (unsigned short)bf16rne(W[k * 128 + n]);
  } else if (gid < 3 * 16384 + 16) {  // zero row NN of the gather table
    ((uint4*)(hbf + (size_t)NN * D))[gid - 3 * 16384] = make_uint4(0, 0, 0, 0);
  }

  // ---- dual LDS histogram ----
  int c = blockIdx.x >> 3;
  int r = blockIdx.x & 7;
  int base = r * NPR;
  for (int i = tid; i < NPR; i += 1024) { hd[i] = 0; hs[i] = 0; }
  __syncthreads();
  int e0 = c * EPC;
  for (int i = tid; i < EPC; i += 1024) {
    int d = dst[e0 + i];
    int s = src[e0 + i];
    unsigned dr = (unsigned)(d - base);
    unsigned sr = (unsigned)(s - base);
    if (dr < NPR) atomicAdd(&hd[dr], 1);
    if (sr < NPR) atomicAdd(&hs[sr], 1);
  }
  __syncthreads();
  for (int i = tid; i < NPR; i += 1024) {
    partial_dst[c * NN + base + i] = hd[i];
    partial_src[c * NN + base + i] = hs[i];
  }
}

__device__ __forceinline__ int block_excl_scan(int v, int* wsum) {
  int lane = threadIdx.x & 63;
  int w = threadIdx.x >> 6;
  int incl = v;
#pragma unroll
  for (int off = 1; off < 64; off <<= 1) {
    int t = __shfl_up(incl, off);
    if (lane >= off) incl += t;
  }
  if (lane == 63) wsum[w] = incl;
  __syncthreads();
  int wo = 0;
#pragma unroll
  for (int j = 0; j < 4; ++j)
    if (j < w) wo += wsum[j];
  return wo + incl - v;
}

// fused reduce + scan phase 1 (padded degree, ceil16)
__global__ __launch_bounds__(256) void degscan_kernel(int* __restrict__ partial_dst,
                                                      const int* __restrict__ partial_src,
                                                      int* __restrict__ degtmp,
                                                      int* __restrict__ deg_out,
                                                      int* __restrict__ row_ptr,
                                                      int* __restrict__ partials, int N) {
  __shared__ int wsum[4];
  int d = blockIdx.x * 256 + threadIdx.x;
  int run = 0;
  if (d < N) {
#pragma unroll
    for (int c = 0; c < CH; ++c) {
      int v = partial_dst[c * NN + d];
      partial_dst[c * NN + d] = run;
      run += v;
    }
    degtmp[d] = run;
    int ro = 0;
#pragma unroll
    for (int c = 0; c < CH; ++c) ro += partial_src[c * NN + d];
    deg_out[d] = ro;
  }
  int pad = (run + 15) & ~15;
  int excl = block_excl_scan(pad, wsum);
  if (d < N) row_ptr[d] = excl;
  if (threadIdx.x == 255) partials[blockIdx.x] = excl + pad;
}

__global__ __launch_bounds__(256) void scan2(int* __restrict__ partials,
                                             int* __restrict__ row_ptr, int nb, int N) {
  __shared__ int wsum[4];
  int v = (threadIdx.x < nb) ? partials[threadIdx.x] : 0;
  int excl = block_excl_scan(v, wsum);
  if (threadIdx.x < nb) partials[threadIdx.x] = excl;
  if (threadIdx.x == nb - 1) row_ptr[N] = excl + v;
}

__global__ __launch_bounds__(256) void scan3(int* __restrict__ row_ptr,
                                             const int* __restrict__ partials, int N) {
  int i = blockIdx.x * 256 + threadIdx.x;
  if (i < N) row_ptr[i] += partials[blockIdx.x];
}

// fill + pad: LDS cursor scatter; chunk-0 blocks also write dummy-index tails.
__global__ __launch_bounds__(1024) void fill_kernel(const int* __restrict__ src,
                                                    const int* __restrict__ dst,
                                                    const int* __restrict__ row_ptr,
                                                    const int* __restrict__ partial_dst,
                                                    const int* __restrict__ degtmp,
                                                    int* __restrict__ csr_src) {
  __shared__ int cur[NPR];
  int tid = threadIdx.x;
  int c = blockIdx.x >> 3;
  int r = blockIdx.x & 7;
  int base = r * NPR;
  for (int i = tid; i < NPR; i += 1024)
    cur[i] = row_ptr[base + i] + partial_dst[c * NN + base + i];
  if (c == 0) {  // pad tails for this node range (disjoint from scatter targets)
    for (int i = tid; i < NPR; i += 1024) {
      int node = base + i;
      int s = row_ptr[node] + degtmp[node];
      int e = row_ptr[node + 1];
      for (int j = s; j < e; ++j) csr_src[j] = NN;
    }
  }
  __syncthreads();
  int e0 = c * EPC;
  for (int i = tid; i < EPC; i += 1024) {
    int d = dst[e0 + i];
    unsigned dr = (unsigned)(d - base);
    if (dr < NPR) {
      int pos = atomicAdd(&cur[dr], 1);
      csr_src[pos] = src[e0 + i];
    }
  }
}

// ---------------- aggregation: one wave per node, quarter-wave per edge ------
// Independent waves (no barrier): 12500 blocks x 4 waves, load imbalance
// absorbed by block refill. Rows padded to x16 -> branch-free 16-deep loop.
// bf16 in, f32 accumulate, bf16 out. MODE 0: sage. MODE 1: gcn rsqrt.
__device__ __forceinline__ void bacc(float* a, uint4 u) {
  a[0] += __uint_as_float(u.x << 16);
  a[1] += __uint_as_float(u.x & 0xffff0000u);
  a[2] += __uint_as_float(u.y << 16);
  a[3] += __uint_as_float(u.y & 0xffff0000u);
  a[4] += __uint_as_float(u.z << 16);
  a[5] += __uint_as_float(u.z & 0xffff0000u);
  a[6] += __uint_as_float(u.w << 16);
  a[7] += __uint_as_float(u.w & 0xffff0000u);
}

template <int MODE>
__global__ __launch_bounds__(256) void agg_kernel(const unsigned short* __restrict__ hb,
                                                  const int* __restrict__ row_ptr,
                                                  const int* __restrict__ csr_src,
                                                  const int* __restrict__ degtmp,
                                                  unsigned short* __restrict__ outb, int N) {
  int wid = blockIdx.x * 4 + (threadIdx.x >> 6);
  int lane = threadIdx.x & 63;
  if (wid >= N) return;
  int start = row_ptr[wid];
  int iters = (row_ptr[wid + 1] - start) >> 4;
  int q = lane >> 4;    // 0..3: which edge in the 4-group
  int col = lane & 15;  // 16B granule within row
  float a0[8] = {0, 0, 0, 0, 0, 0, 0, 0};
  float a1[8] = {0, 0, 0, 0, 0, 0, 0, 0};
  float a2[8] = {0, 0, 0, 0, 0, 0, 0, 0};
  float a3[8] = {0, 0, 0, 0, 0, 0, 0, 0};
  const int* ce = csr_src + start + q;
  for (int it = 0; it < iters; ++it, ce += 16) {
    int i0 = ce[0];
    int i1 = ce[4];
    int i2 = ce[8];
    int i3 = ce[12];
    uint4 u0 = ((const uint4*)(hb + (size_t)i0 * D))[col];
    uint4 u1 = ((const uint4*)(hb + (size_t)i1 * D))[col];
    uint4 u2 = ((const uint4*)(hb + (size_t)i2 * D))[col];
    uint4 u3 = ((const uint4*)(hb + (size_t)i3 * D))[col];
    bacc(a0, u0);
    bacc(a1, u1);
    bacc(a2, u2);
    bacc(a3, u3);
  }
#pragma unroll
  for (int j = 0; j < 8; ++j) a0[j] = (a0[j] + a1[j]) + (a2[j] + a3[j]);
#pragma unroll
  for (int j = 0; j < 8; ++j) {
    a0[j] += __shfl_xor(a0[j], 16);
    a0[j] += __shfl_xor(a0[j], 32);
  }
  int indeg = degtmp[wid];
  if (MODE == 0) {
    uint4 s = ((const uint4*)(hb + (size_t)wid * D))[col];
    float sf[8] = {0, 0, 0, 0, 0, 0, 0, 0};
    bacc(sf, s);
    float inv = 1.0f / (float)(indeg + 1);
#pragma unroll
    for (int j = 0; j < 8; ++j) a0[j] = (a0[j] + sf[j]) * inv;
  } else {
    float sc = rsqrtf(fmaxf((float)indeg, 1.0f));
#pragma unroll
    for (int j = 0; j < 8; ++j) a0[j] *= sc;
  }
  if (q == 0) {
    uint4 p;
    p.x = packbf(a0[0], a0[1]);
    p.y = packbf(a0[2], a0[3]);
    p.z = packbf(a0[4], a0[5]);
    p.w = packbf(a0[6], a0[7]);
    ((uint4*)(outb + (size_t)wid * D))[col] = p;
  }
}

// ---------------- MFMA GEMM: [N x 128](bf16) @ [128 x 128] + bias ------------
// 256 thr = 4 waves; block tile 64 rows; wave tile 16 rows x 128 cols.
// WT (=W^T, [n][k]) staged in LDS, row stride 136 (2-way conflict = free).
// MODE 1: scale rows by rsqrt(max(deg_out,1)). OUT_BF 1: write bf16 table.
template <int MODE, int OUT_BF>
__global__ __launch_bounds__(256) void mgemm_kernel(const unsigned short* __restrict__ A,
                                                    const unsigned short* __restrict__ WT,
                                                    const float* __restrict__ bias,
                                                    const int* __restrict__ deg_out,
                                                    float* __restrict__ outf,
                                                    unsigned short* __restrict__ outb, int N) {
  __shared__ unsigned short sWT[128 * 136];
  int tid = threadIdx.x;
  for (int g = tid; g < 2048; g += 256) {
    int n = g >> 4, c = g & 15;
    uint4 v = ((const uint4*)WT)[g];
    *(uint4*)&sWT[n * 136 + c * 8] = v;
  }
  int wv = tid >> 6;
  int lane = tid & 63;
  int q = lane >> 4;
  int ln = lane & 15;
  int row0 = blockIdx.x * 64 + wv * 16;
  int arow = row0 + ln;
  if (arow >= N) arow = 0;  // clamp; stores are guarded
  const unsigned short* Ar = A + (size_t)arow * 128 + q * 8;
  bf16x8 af0 = *(const bf16x8*)(Ar + 0);
  bf16x8 af1 = *(const bf16x8*)(Ar + 32);
  bf16x8 af2 = *(const bf16x8*)(Ar + 64);
  bf16x8 af3 = *(const bf16x8*)(Ar + 96);
  f32x4 acc[8];
#pragma unroll
  for (int t = 0; t < 8; ++t) acc[t] = (f32x4){0.f, 0.f, 0.f, 0.f};
  __syncthreads();
#pragma unroll
  for (int t = 0; t < 8; ++t) {
    const unsigned short* Wr = &sWT[(t * 16 + ln) * 136 + q * 8];
    bf16x8 b0 = *(const bf16x8*)(Wr + 0);
    bf16x8 b1 = *(const bf16x8*)(Wr + 32);
    bf16x8 b2 = *(const bf16x8*)(Wr + 64);
    bf16x8 b3 = *(const bf16x8*)(Wr + 96);
    acc[t] = __builtin_amdgcn_mfma_f32_16x16x32_bf16(af0, b0, acc[t], 0, 0, 0);
    acc[t] = __builtin_amdgcn_mfma_f32_16x16x32_bf16(af1, b1, acc[t], 0, 0, 0);
    acc[t] = __builtin_amdgcn_mfma_f32_16x16x32_bf16(af2, b2, acc[t], 0, 0, 0);
    acc[t] = __builtin_amdgcn_mfma_f32_16x16x32_bf16(af3, b3, acc[t], 0, 0, 0);
  }
  float scl[4];
#pragma unroll
  for (int r = 0; r < 4; ++r) {
    scl[r] = 1.0f;
    if (MODE == 1) {
      int row = row0 + q * 4 + r;
      int rr = (row < N) ? row : 0;
      scl[r] = rsqrtf(fmaxf((float)deg_out[rr], 1.0f));
    }
  }
#pragma unroll
  for (int t = 0; t < 8; ++t) {
    float b = bias[t * 16 + ln];
#pragma unroll
    for (int r = 0; r < 4; ++r) {
      int row = row0 + q * 4 + r;
      if (row < N) {
        float v = (acc[t][r] + b) * scl[r];
        if (OUT_BF)
          outb[(size_t)row * 128 + t * 16 + ln] = (unsigned short)bf16rne(v);
        else
          outf[(size_t)row * 128 + t * 16 + ln] = v;
      }
    }
  }
}

// ---------------- launcher ----------------

extern "C" void kernel_launch(void* const* d_in, const int* in_sizes, int n_in,
                              void* d_out, int out_size, void* d_ws, size_t ws_size,
                              hipStream_t stream) {
  const float* x = (const float*)d_in[0];
  const float* W1 = (const float*)d_in[1];
  const float* b1 = (const float*)d_in[2];
  const float* W2 = (const float*)d_in[3];
  const float* b2 = (const float*)d_in[4];
  const float* W3 = (const float*)d_in[5];
  const float* b3 = (const float*)d_in[6];
  const int* src = (const int*)d_in[7];
  const int* dst = (const int*)d_in[8];
  float* out = (float*)d_out;

  const int N = NN;

  // workspace layout (~58 MB)
  unsigned short* hbf = (unsigned short*)d_ws;             // (NN+1)*D bf16 gather tbl
  unsigned short* aggB = hbf + (size_t)(NN + 1) * D;       // NN*D bf16 agg out
  unsigned short* WT1 = aggB + (size_t)NN * D;             // 128*128 bf16
  unsigned short* WT2 = WT1 + D * D;
  unsigned short* WT3 = WT2 + D * D;
  int* partial_dst = (int*)(WT3 + D * D);                  // CH*NN
  int* partial_src = partial_dst + (size_t)CH * NN;        // CH*NN
  int* degtmp = partial_src + (size_t)CH * NN;             // NN
  int* deg_out = degtmp + NN;                              // NN
  int* row_ptr = deg_out + NN;                             // NN+1
  int* partials = row_ptr + NN + 1;                        // 256
  int* csr_src = partials + 256;                           // NE + 16*NN

  const int scanBlocks = (N + 255) / 256;  // 196

  hist_kernel<<<CH * RG, 1024, 0, stream>>>(src, dst, x, W1, W2, W3, hbf,
                                            WT1, WT2, WT3, partial_dst, partial_src);
  degscan_kernel<<<scanBlocks, 256, 0, stream>>>(partial_dst, partial_src, degtmp,
                                                 deg_out, row_ptr, partials, N);
  scan2<<<1, 256, 0, stream>>>(partials, row_ptr, scanBlocks, N);
  scan3<<<scanBlocks, 256, 0, stream>>>(row_ptr, partials, N);
  fill_kernel<<<CH * RG, 1024, 0, stream>>>(src, dst, row_ptr, partial_dst, degtmp, csr_src);

  int aggBlocks = (N + 3) / 4;     // 12500: 1 node/wave, no barrier
  int gemmBlocks = (N + 63) / 64;  // 782

  // layer 1: sage(x)@W1+b1
  agg_kernel<0><<<aggBlocks, 256, 0, stream>>>(hbf, row_ptr, csr_src, degtmp, aggB, N);
  mgemm_kernel<0, 1><<<gemmBlocks, 256, 0, stream>>>(aggB, WT1, b1, deg_out, nullptr, hbf, N);
  // layer 2: sage(h1)@W2+b2, fold norm_out for layer 3
  agg_kernel<0><<<aggBlocks, 256, 0, stream>>>(hbf, row_ptr, csr_src, degtmp, aggB, N);
  mgemm_kernel<1, 1><<<gemmBlocks, 256, 0, stream>>>(aggB, WT2, b2, deg_out, nullptr, hbf, N);
  // layer 3: gcn agg(h2)*norm_in @ W3 + b3 -> out (f32)
  agg_kernel<1><<<aggBlocks, 256, 0, stream>>>(hbf, row_ptr, csr_src, degtmp, aggB, N);
  mgemm_kernel<0, 0><<<gemmBlocks, 256, 0, stream>>>(aggB, WT3, b3, deg_out, out, nullptr, N);
}